// Round 4
// baseline (11.858 us; speedup 1.0000x reference)
//
#include <hip/hip_runtime.h>

// Problem constants (B,C,H,W = 2,512,64,64; 8 heads x 64 dim)
namespace {
constexpr int kC      = 512;
constexpr int kHW     = 4096;              // 64*64
constexpr int kB      = 2;
constexpr int kBlocks = kB * kC * 2;       // 2 blocks per (batch, channel): 2048
}

// out[b,o,y,x] = x[b,o,y,x]
//              + rowsum(w_proj[o,:]) * 4096 * b_qkv[1024 + (x&7)*64 + (y&7)*8 + (x>>3)]
//              + b_proj[o]
//
// Derivation: einsum('bnqk,bnvd') = rowsum(softmax)=1 (outer) colsum(v);
// colsum(v) = HW*b_qkv_v because the spatial sum of InstanceNorm output is
// identically 0 (so w_qkv and x's statistics drop out). The faithful
// permute(0,2,3,1).reshape makes the added term channel-independent, so
// w_proj enters only via its row-sums.
//
// Structure notes:
// - 2048 blocks x 256 threads, 2 float4/thread: finer tail quantum.
// - load order wrow -> bq -> x: the shfl reduction waits only on the
//   early loads (vmcnt(8)) while the x stream is still in flight.
// - per-WAVE w_proj row-sum (shfl_xor): no LDS, no __syncthreads.
// - j's bits 4-6 (y&7) and 0-3 (x&15) come purely from tid, so the
//   b_qkv additive term is invariant across r and the half-plane bit.
__global__ __launch_bounds__(256) void fused_attn_collapse_kernel(
        const float* __restrict__ x,
        const float* __restrict__ b_qkv,
        const float* __restrict__ b_proj,
        const float* __restrict__ w_proj,
        float* __restrict__ out) {
    const int blk  = blockIdx.x;
    const int bo   = blk >> 1;             // batch*512 + channel
    const int half = blk & 1;              // which half of the 4096-pixel plane
    const int o    = bo & (kC - 1);
    const int tid  = threadIdx.x;          // 0..255
    const int lane = tid & 63;

    // (1) w-row first: the reduction's waitcnt then leaves x in flight.
    const float4* __restrict__ wrow4 = reinterpret_cast<const float4*>(w_proj + o * kC);
    const float4 wa = wrow4[lane * 2 + 0];
    const float4 wb = wrow4[lane * 2 + 1];

    // (2) b_qkv term pattern: bits 4-6 / 0-3 of j depend only on tid.
    const int x0   = (tid & 15) << 2;
    const int base = 1024 + (((tid >> 4) & 7) << 3) + (x0 >> 3);
    const int n0   = x0 & 7;               // 0 or 4
    const float bq0 = b_qkv[base + (n0 + 0) * 64];
    const float bq1 = b_qkv[base + (n0 + 1) * 64];
    const float bq2 = b_qkv[base + (n0 + 2) * 64];
    const float bq3 = b_qkv[base + (n0 + 3) * 64];

    // (3) x loads last.
    const float4* __restrict__ xin =
        reinterpret_cast<const float4*>(x) + bo * (kHW / 4) + half * 512;
    const float4 xv0 = xin[tid];
    const float4 xv1 = xin[tid + 256];

    // Per-wave row-sum of w_proj[o,:]: 8 floats/lane, 6-step shfl_xor tree.
    float s = (wa.x + wa.y + wa.z + wa.w) + (wb.x + wb.y + wb.z + wb.w);
    #pragma unroll
    for (int off = 32; off > 0; off >>= 1) s += __shfl_xor(s, off);

    const float w4096 = s * 4096.f;
    const float bp    = b_proj[o];
    float4 term;
    term.x = fmaf(w4096, bq0, bp);
    term.y = fmaf(w4096, bq1, bp);
    term.z = fmaf(w4096, bq2, bp);
    term.w = fmaf(w4096, bq3, bp);

    float4* __restrict__ oout =
        reinterpret_cast<float4*>(out) + bo * (kHW / 4) + half * 512;
    float4 ov0, ov1;
    ov0.x = xv0.x + term.x;  ov0.y = xv0.y + term.y;
    ov0.z = xv0.z + term.z;  ov0.w = xv0.w + term.w;
    oout[tid] = ov0;
    ov1.x = xv1.x + term.x;  ov1.y = xv1.y + term.y;
    ov1.z = xv1.z + term.z;  ov1.w = xv1.w + term.w;
    oout[tid + 256] = ov1;
}

extern "C" void kernel_launch(void* const* d_in, const int* in_sizes, int n_in,
                              void* d_out, int out_size, void* d_ws, size_t ws_size,
                              hipStream_t stream) {
    const float* x      = (const float*)d_in[0];
    // d_in[1] = w_qkv: unused — it reaches the output only through
    // sum_spatial(instancenorm(x)) == 0.
    const float* b_qkv  = (const float*)d_in[2];
    const float* w_proj = (const float*)d_in[3];
    const float* b_proj = (const float*)d_in[4];
    float* out = (float*)d_out;

    fused_attn_collapse_kernel<<<kBlocks, 256, 0, stream>>>(x, b_qkv, b_proj, w_proj, out);
}

// Round 5
// 11.056 us; speedup vs baseline: 1.0725x; 1.0725x over previous
//
#include <hip/hip_runtime.h>

// Problem constants (B,C,H,W = 2,512,64,64; 8 heads x 64 dim)
namespace {
constexpr int kC      = 512;
constexpr int kHW     = 4096;              // 64*64
constexpr int kB      = 2;
constexpr int kBlocks = kB * kC;           // one block per (batch, channel): 1024
}

// out[b,o,y,x] = x[b,o,y,x]
//              + rowsum(w_proj[o,:]) * 4096 * b_qkv[1024 + (x&7)*64 + (y&7)*8 + (x>>3)]
//              + b_proj[o]
//
// Derivation: einsum('bnqk,bnvd') = rowsum(softmax)=1 (outer) colsum(v);
// colsum(v) = HW*b_qkv_v because the spatial sum of InstanceNorm output is
// identically 0 (so w_qkv and x's statistics drop out). The faithful
// permute(0,2,3,1).reshape makes the added term channel-independent, so
// w_proj enters only via its row-sums.
//
// Best measured variant (round 3, 11.32 us): 1024 blocks x 256 threads,
// 4 float4/thread, per-wave shfl_xor reduction (no LDS / no barrier),
// b_qkv term hoisted (invariant across the 4 r-iterations).
__global__ __launch_bounds__(256) void fused_attn_collapse_kernel(
        const float* __restrict__ x,
        const float* __restrict__ b_qkv,
        const float* __restrict__ b_proj,
        const float* __restrict__ w_proj,
        float* __restrict__ out) {
    const int bo   = blockIdx.x;           // batch*512 + channel
    const int o    = bo & (kC - 1);
    const int tid  = threadIdx.x;          // 0..255
    const int lane = tid & 63;

    // Issue the x loads immediately — they cover everything else.
    const float4* __restrict__ xin = reinterpret_cast<const float4*>(x) + bo * (kHW / 4);
    float4 xv[4];
    #pragma unroll
    for (int r = 0; r < 4; ++r) xv[r] = xin[tid + r * 256];

    // b_qkv term pattern (invariant across the 4 r-iterations):
    //   x0 = (j&15)<<2, y&7 = (j>>4)&7  — both depend only on tid.
    const int x0   = (tid & 15) << 2;
    const int base = 1024 + (((tid >> 4) & 7) << 3) + (x0 >> 3);
    const int n0   = x0 & 7;               // 0 or 4
    const float bq0 = b_qkv[base + (n0 + 0) * 64];
    const float bq1 = b_qkv[base + (n0 + 1) * 64];
    const float bq2 = b_qkv[base + (n0 + 2) * 64];
    const float bq3 = b_qkv[base + (n0 + 3) * 64];

    // Per-wave row-sum of w_proj[o,:]: lane reads 8 consecutive floats
    // (two float4), local sum, then 6-step shfl_xor tree -> all lanes hold s.
    const float4* __restrict__ wrow4 = reinterpret_cast<const float4*>(w_proj + o * kC);
    const float4 wa = wrow4[lane * 2 + 0];
    const float4 wb = wrow4[lane * 2 + 1];
    float s = (wa.x + wa.y + wa.z + wa.w) + (wb.x + wb.y + wb.z + wb.w);
    #pragma unroll
    for (int off = 32; off > 0; off >>= 1) s += __shfl_xor(s, off);

    const float w4096 = s * 4096.f;
    const float bp    = b_proj[o];
    float4 term;
    term.x = fmaf(w4096, bq0, bp);
    term.y = fmaf(w4096, bq1, bp);
    term.z = fmaf(w4096, bq2, bp);
    term.w = fmaf(w4096, bq3, bp);

    float4* __restrict__ oout = reinterpret_cast<float4*>(out) + bo * (kHW / 4);
    #pragma unroll
    for (int r = 0; r < 4; ++r) {
        float4 ov;
        ov.x = xv[r].x + term.x;
        ov.y = xv[r].y + term.y;
        ov.z = xv[r].z + term.z;
        ov.w = xv[r].w + term.w;
        oout[tid + r * 256] = ov;
    }
}

extern "C" void kernel_launch(void* const* d_in, const int* in_sizes, int n_in,
                              void* d_out, int out_size, void* d_ws, size_t ws_size,
                              hipStream_t stream) {
    const float* x      = (const float*)d_in[0];
    // d_in[1] = w_qkv: unused — it reaches the output only through
    // sum_spatial(instancenorm(x)) == 0.
    const float* b_qkv  = (const float*)d_in[2];
    const float* w_proj = (const float*)d_in[3];
    const float* b_proj = (const float*)d_in[4];
    float* out = (float*)d_out;

    fused_attn_collapse_kernel<<<kBlocks, 256, 0, stream>>>(x, b_qkv, b_proj, w_proj, out);
}